// Round 11
// baseline (3304.341 us; speedup 1.0000x reference)
//
#include <hip/hip_runtime.h>
#include <hip/hip_bf16.h>
#include <stdint.h>

// Problem constants
#define B_    64
#define HP_   16
#define WP_   32
#define CH_   512
#define HS_   512
#define NSEQ  1024      // B_*HP_
#define G4    2048      // 4*HS_
#define KTOT  1024      // CH_ + HS_ (concat Wi;Wh)

typedef __hip_bfloat16 bf16_t;
typedef __bf16 bf16x8 __attribute__((ext_vector_type(8)));
typedef float  f32x4  __attribute__((ext_vector_type(4)));

// ---------------- workspace layout (bytes) ----------------
#define WT_OFF   0            // Wt   bf16 [4][2048][1024]  (16 MB)
#define XBF_OFF  16777216     // xbf  bf16 [32][1024][512]  (32 MB)
#define HBUF_OFF 50331648     // hbuf bf16 [2][2][2][1024][512] (8 MB)
#define CBUF_OFF 58720256     // cbuf f32  [2][2][1024][512] (8 MB)
#define PB_OFF   67108864     // pb   f32  [4][2048] (32 KB)
#define CNT_OFF  (PB_OFF + 32768)  // uint32 grid-barrier counter
#define HB_ELEMS (2*2*1024*512)

__device__ __forceinline__ float sigf(float x) {
    return 1.0f / (1.0f + __expf(-x));
}
__device__ __forceinline__ float tanhfast(float x) {
    x = fminf(fmaxf(x, -15.0f), 15.0f);
    float e = __expf(-2.0f * x);
    return (1.0f - e) / (1.0f + e);
}

__device__ __forceinline__ void gload16(const bf16_t* g, bf16_t* l) {
    __builtin_amdgcn_global_load_lds(
        (const __attribute__((address_space(1))) void*)g,
        (__attribute__((address_space(3))) void*)l, 16, 0, 0);
}

// ------------- prep: transpose + gate-permute weights to bf16 [u][c'][k] -------------
__global__ void k_prep_w(const float* __restrict__ Wi_fw, const float* __restrict__ Wh_fw,
                         const float* __restrict__ Wi_bw, const float* __restrict__ Wh_bw,
                         bf16_t* __restrict__ Wt) {
    int bxi = blockIdx.x;
    int cb = bxi & 63;
    int kb = (bxi >> 6) & 31;
    int u  = bxi >> 11;          // 0:fw-L0 1:bw-L0 2:fw-L1 3:bw-L1
    int l  = u >> 1, dir = u & 1;
    const float* Wi = dir ? Wi_bw : Wi_fw;
    const float* Wh = dir ? Wh_bw : Wh_fw;
    int k0 = kb * 32;
    const float* src = (k0 < 512) ? (Wi + (size_t)l*512*2048 + (size_t)k0*2048)
                                  : (Wh + (size_t)l*512*2048 + (size_t)(k0-512)*2048);
    int jblk = cb >> 2, g = cb & 3;
    int sc0 = g*512 + jblk*32;   // source col base (gate-major)
    int cp0 = cb * 32;           // permuted c' base
    __shared__ float ld[32][33];
    int tx = threadIdx.x & 31, ty = threadIdx.x >> 5;
#pragma unroll
    for (int i = 0; i < 4; ++i) {
        int kr = ty + i*8;
        ld[kr][tx] = src[(size_t)kr*2048 + sc0 + tx];
    }
    __syncthreads();
#pragma unroll
    for (int i = 0; i < 4; ++i) {
        int cl = ty + i*8;
        Wt[((size_t)u*G4 + cp0 + cl)*KTOT + k0 + tx] = __float2bfloat16(ld[tx][cl]);
    }
}

// ------------- prep: permuted combined bias (+ zero grid-barrier counter) -------------
__global__ void k_prep_bias(const float* __restrict__ bi_fw, const float* __restrict__ bh_fw,
                            const float* __restrict__ bi_bw, const float* __restrict__ bh_bw,
                            float* __restrict__ pb, uint32_t* __restrict__ cnt) {
    int id = blockIdx.x * 256 + threadIdx.x;
    if (id == 0) *cnt = 0;       // re-zero every call (ws is re-poisoned by harness)
    if (id >= 4*G4) return;
    int u = id >> 11, cp = id & 2047;
    int l = u >> 1, dir = u & 1;
    int jblk = cp >> 7, rr = cp & 127, g = rr >> 5, jin = rr & 31;
    int col = g*512 + jblk*32 + jin;
    const float* bi = dir ? bi_bw : bi_fw;
    const float* bh = dir ? bh_bw : bh_fw;
    pb[id] = bi[l*G4 + col] + bh[l*G4 + col];
}

// ------------- prep: features -> time-major bf16 -------------
__global__ void k_convert_x(const float* __restrict__ f, bf16_t* __restrict__ xbf) {
    int id = blockIdx.x * 256 + threadIdx.x;
    int c8 = id & 63;
    int t  = (id >> 6) & 31;
    int n  = id >> 11;
    const float* s = f + ((size_t)n*WP_ + t)*CH_ + c8*8;
    bf16_t* d = xbf + ((size_t)t*NSEQ + n)*CH_ + c8*8;
#pragma unroll
    for (int i = 0; i < 8; ++i) d[i] = __float2bfloat16(s[i]);
}

// ------------- prep: init h (bf16) / c (f32) from pos_emb -------------
__global__ void k_init_state(const float* __restrict__ pe_fw, const float* __restrict__ pe_bw,
                             bf16_t* __restrict__ hbuf, float* __restrict__ cbuf) {
    int id = blockIdx.x * 256 + threadIdx.x;
    int j = id & 511;
    int n = (id >> 9) & 1023;
    int l = (id >> 19) & 1;
    int dir = id >> 20;
    const float* pe = dir ? pe_bw : pe_fw;
    int rowi = (n & 15) + 1;
    float h = pe[(size_t)rowi*2048 + l*1024 + j];
    float c = pe[(size_t)rowi*2048 + l*1024 + 512 + j];
    int pp = (l == 0) ? 1 : 0;
    hbuf[(size_t)pp*HB_ELEMS + (((size_t)dir*2 + l)*NSEQ + n)*HS_ + j] = __float2bfloat16(h);
    cbuf[(((size_t)dir*2 + l)*NSEQ + n)*HS_ + j] = c;
}

// ------------- persistent kernel: all 33 wavefront phases, spin grid-barrier -------------
// 512 blocks x 256 thr = exactly 2 blocks/CU (64 KB LDS each) -> all co-resident.
// Inner K-loop identical to R10 (counted vmcnt(8) pipeline, LDS dbuf, XOR swizzle).
__global__ __launch_bounds__(256, 2) void k_persist(
    const bf16_t* __restrict__ xbf,
    const bf16_t* __restrict__ Wt,
    const float*  __restrict__ pb,
    bf16_t* __restrict__ hbuf,
    float*  __restrict__ cbuf,
    float*  __restrict__ out,
    uint32_t* __restrict__ cnt) {

    int bx = blockIdx.x;
    int xcd   = bx & 7;
    int layer = (bx >> 8) & 1;
    int r5    = (bx >> 3) & 31;
    int dir   = r5 & 1;
    int cb    = xcd * 2 + ((r5 >> 1) & 1);
    int rb    = r5 >> 2;
    int u     = layer * 2 + dir;

    int row0 = rb * 128;
    int c0 = cb * 128;

    const bf16_t* Wu = Wt + (size_t)u * G4 * KTOT;

    __shared__ __align__(16) bf16_t a_lds[2][128*64];
    __shared__ __align__(16) bf16_t b_lds[2][128*64];

    int tid = threadIdx.x;
    int lane = tid & 63;
    int wv = tid >> 6;

    // hoisted per-block invariants
    float bias[4][2];
#pragma unroll
    for (int g = 0; g < 4; ++g)
#pragma unroll
        for (int jq = 0; jq < 2; ++jq)
            bias[g][jq] = pb[u*G4 + c0 + g*32 + jq*16 + (lane & 15)];
    float* cptr = cbuf + ((size_t)dir*2 + layer) * NSEQ * HS_;

#pragma unroll 1
    for (int p = 0; p <= WP_; ++p) {
        bool active = !(layer == 0 && p >= WP_) && !(layer == 1 && p < 1);
        if (active) {
            const bf16_t* hread = hbuf + (size_t)((p + 1) & 1) * HB_ELEMS;
            bf16_t* hwrite      = hbuf + (size_t)(p & 1) * HB_ELEMS;

            const bf16_t* A1;
            const bf16_t* A2;
            int t_out = 0;
            if (layer == 0) {
                int t = dir ? (WP_ - 1 - p) : p;
                A1 = xbf + (size_t)t * NSEQ * CH_;
                A2 = hread + ((size_t)dir*2 + 0) * NSEQ * HS_;
            } else {
                A1 = hread + ((size_t)dir*2 + 0) * NSEQ * HS_;   // h0(t=p-1)
                A2 = hread + ((size_t)dir*2 + 1) * NSEQ * HS_;   // h1(t=p-2)
                t_out = dir ? (WP_ - p) : (p - 1);
            }

            f32x4 acc[2][8];
#pragma unroll
            for (int m = 0; m < 2; ++m)
#pragma unroll
                for (int n = 0; n < 8; ++n)
                    acc[m][n] = (f32x4){0.f, 0.f, 0.f, 0.f};

            auto STAGE = [&](int kt, int bufi) {
                const bf16_t* Asrc;
                int kloc;
                if (kt < 8) { Asrc = A1; kloc = kt * 64; }
                else        { Asrc = A2; kloc = kt * 64 - 512; }
#pragma unroll
                for (int q = 0; q < 4; ++q) {
                    int id = q*256 + tid;
                    int r = id >> 3;
                    int s = id & 7;
                    int kk = ((s ^ (r & 7)) << 3);
                    gload16(Asrc + (size_t)(row0 + r)*512 + kloc + kk,
                            a_lds[bufi] + (size_t)(q*256 + (wv << 6)) * 8);
                }
#pragma unroll
                for (int q = 0; q < 4; ++q) {
                    int id = q*256 + tid;
                    int r = id >> 3;
                    int s = id & 7;
                    int kk = ((s ^ (r & 7)) << 3);
                    gload16(Wu + (size_t)(c0 + r)*KTOT + kt*64 + kk,
                            b_lds[bufi] + (size_t)(q*256 + (wv << 6)) * 8);
                }
            };

            auto COMPUTE = [&](int bufi) {
                const char* ac = (const char*)a_lds[bufi];
                const char* bc = (const char*)b_lds[bufi];
#pragma unroll
                for (int ks = 0; ks < 2; ++ks) {
                    int kb = (ks << 5) + ((lane >> 4) << 3);
                    bf16x8 av[2], bv[8];
#pragma unroll
                    for (int m = 0; m < 2; ++m) {
                        int row = (wv << 5) + (m << 4) + (lane & 15);
                        int byte = row*128 + kb*2;
                        byte ^= (row & 7) << 4;
                        av[m] = *(const bf16x8*)(ac + byte);
                    }
#pragma unroll
                    for (int n = 0; n < 8; ++n) {
                        int colr = (n << 4) + (lane & 15);
                        int byte = colr*128 + kb*2;
                        byte ^= (colr & 7) << 4;
                        bv[n] = *(const bf16x8*)(bc + byte);
                    }
#pragma unroll
                    for (int m = 0; m < 2; ++m)
#pragma unroll
                        for (int n = 0; n < 8; ++n)
                            acc[m][n] = __builtin_amdgcn_mfma_f32_16x16x32_bf16(av[m], bv[n], acc[m][n], 0, 0, 0);
                }
            };

            STAGE(0, 0);
            int cur = 0;
#pragma unroll 1
            for (int kt = 0; kt < 15; ++kt) {
                STAGE(kt + 1, cur ^ 1);                          // 16 outstanding
                asm volatile("s_waitcnt vmcnt(8)" ::: "memory"); // tile kt landed
                __builtin_amdgcn_s_barrier();
                COMPUTE(cur);                                    // overlaps kt+1 loads
                __builtin_amdgcn_s_barrier();
                cur ^= 1;
            }
            asm volatile("s_waitcnt vmcnt(0)" ::: "memory");
            __builtin_amdgcn_s_barrier();
            COMPUTE(cur);

            // ---- epilogue: lane-local LSTM pointwise ----
            bf16_t* hw = hwrite + ((size_t)dir*2 + layer) * NSEQ * HS_;
#pragma unroll
            for (int m = 0; m < 2; ++m) {
#pragma unroll
                for (int jq = 0; jq < 2; ++jq) {
                    f32x4 iv = acc[m][0 + jq];
                    f32x4 fv = acc[m][2 + jq];
                    f32x4 ov = acc[m][4 + jq];
                    f32x4 gv = acc[m][6 + jq];
                    int j = cb*32 + jq*16 + (lane & 15);
#pragma unroll
                    for (int r = 0; r < 4; ++r) {
                        int row = (wv << 5) + (m << 4) + ((lane >> 4) << 2) + r;
                        int n = row0 + row;
                        float ig = sigf(iv[r] + bias[0][jq]);
                        float fg = sigf(fv[r] + bias[1][jq]);
                        float og = sigf(ov[r] + bias[2][jq]);
                        float gg = tanhfast(gv[r] + bias[3][jq]);
                        size_t sidx = (size_t)n * HS_ + j;
                        float cp = cptr[sidx];
                        float cn = fg * cp + ig * gg;
                        float hn = og * tanhfast(cn);
                        cptr[sidx] = cn;
                        hw[sidx] = __float2bfloat16(hn);
                        if (layer == 1)
                            out[((size_t)n * WP_ + t_out) * (2*HS_) + (size_t)dir*HS_ + j] = hn;
                    }
                }
            }
        }

        // ---- device-scope grid barrier (monotonic counter) ----
        __syncthreads();    // all block threads' stores drained (vmcnt 0) before arrival
        if (tid == 0) {
            __threadfence();
            __hip_atomic_fetch_add(cnt, 1u, __ATOMIC_RELEASE, __HIP_MEMORY_SCOPE_AGENT);
            uint32_t target = (uint32_t)(p + 1) * 512u;
            while (__hip_atomic_load(cnt, __ATOMIC_ACQUIRE, __HIP_MEMORY_SCOPE_AGENT) < target)
                __builtin_amdgcn_s_sleep(2);
        }
        __syncthreads();    // whole block waits for thread0's acquire
    }
}

extern "C" void kernel_launch(void* const* d_in, const int* in_sizes, int n_in,
                              void* d_out, int out_size, void* d_ws, size_t ws_size,
                              hipStream_t stream) {
    const float* features = (const float*)d_in[0];
    const float* pe_fw = (const float*)d_in[1];
    const float* pe_bw = (const float*)d_in[2];
    const float* Wi_fw = (const float*)d_in[3];
    const float* Wh_fw = (const float*)d_in[4];
    const float* bi_fw = (const float*)d_in[5];
    const float* bh_fw = (const float*)d_in[6];
    const float* Wi_bw = (const float*)d_in[7];
    const float* Wh_bw = (const float*)d_in[8];
    const float* bi_bw = (const float*)d_in[9];
    const float* bh_bw = (const float*)d_in[10];

    char* ws = (char*)d_ws;
    bf16_t* Wt   = (bf16_t*)(ws + WT_OFF);
    bf16_t* xbf  = (bf16_t*)(ws + XBF_OFF);
    bf16_t* hbuf = (bf16_t*)(ws + HBUF_OFF);
    float*  cbuf = (float*)(ws + CBUF_OFF);
    float*  pb   = (float*)(ws + PB_OFF);
    uint32_t* cnt = (uint32_t*)(ws + CNT_OFF);
    float*  out  = (float*)d_out;

    k_prep_w<<<dim3(8192), dim3(256), 0, stream>>>(Wi_fw, Wh_fw, Wi_bw, Wh_bw, Wt);
    k_prep_bias<<<dim3(32), dim3(256), 0, stream>>>(bi_fw, bh_fw, bi_bw, bh_bw, pb, cnt);
    k_convert_x<<<dim3(8192), dim3(256), 0, stream>>>(features, xbf);
    k_init_state<<<dim3(8192), dim3(256), 0, stream>>>(pe_fw, pe_bw, hbuf, cbuf);

    k_persist<<<dim3(512), dim3(256), 0, stream>>>(xbf, Wt, pb, hbuf, cbuf, out, cnt);
}

// Round 15
// 1078.515 us; speedup vs baseline: 3.0638x; 3.0638x over previous
//
#include <hip/hip_runtime.h>
#include <hip/hip_bf16.h>
#include <stdint.h>

// Problem constants
#define B_    64
#define HP_   16
#define WP_   32
#define CH_   512
#define HS_   512
#define NSEQ  1024      // B_*HP_
#define G4    2048      // 4*HS_
#define KTOT  1024      // CH_ + HS_ (concat Wi;Wh)

typedef __hip_bfloat16 bf16_t;
typedef __bf16 bf16x8 __attribute__((ext_vector_type(8)));
typedef float  f32x4  __attribute__((ext_vector_type(4)));

// ---------------- workspace layout (bytes) ----------------
#define WT_OFF   0            // Wt   bf16 [4][2048][1024]  (16 MB)
#define XBF_OFF  16777216     // xbf  bf16 [32][1024][512]  (32 MB)
#define HBUF_OFF 50331648     // hbuf bf16 [2][2][2][1024][512] (8 MB)
#define CBUF_OFF 58720256     // cbuf f32  [2][2][1024][512] (8 MB)
#define PB_OFF   67108864     // pb   f32  [4][2048]
#define HB_ELEMS (2*2*1024*512)

__device__ __forceinline__ float sigf(float x) {
    return 1.0f / (1.0f + __expf(-x));
}
__device__ __forceinline__ float tanhfast(float x) {
    x = fminf(fmaxf(x, -15.0f), 15.0f);
    float e = __expf(-2.0f * x);
    return (1.0f - e) / (1.0f + e);
}

__device__ __forceinline__ void gload16(const bf16_t* g, bf16_t* l) {
    __builtin_amdgcn_global_load_lds(
        (const __attribute__((address_space(1))) void*)g,
        (__attribute__((address_space(3))) void*)l, 16, 0, 0);
}

// ------------- prep: transpose + gate-permute weights to bf16 [u][c'][k] -------------
__global__ void k_prep_w(const float* __restrict__ Wi_fw, const float* __restrict__ Wh_fw,
                         const float* __restrict__ Wi_bw, const float* __restrict__ Wh_bw,
                         bf16_t* __restrict__ Wt) {
    int bxi = blockIdx.x;
    int cb = bxi & 63;
    int kb = (bxi >> 6) & 31;
    int u  = bxi >> 11;          // 0:fw-L0 1:bw-L0 2:fw-L1 3:bw-L1
    int l  = u >> 1, dir = u & 1;
    const float* Wi = dir ? Wi_bw : Wi_fw;
    const float* Wh = dir ? Wh_bw : Wh_fw;
    int k0 = kb * 32;
    const float* src = (k0 < 512) ? (Wi + (size_t)l*512*2048 + (size_t)k0*2048)
                                  : (Wh + (size_t)l*512*2048 + (size_t)(k0-512)*2048);
    int jblk = cb >> 2, g = cb & 3;
    int sc0 = g*512 + jblk*32;   // source col base (gate-major)
    int cp0 = cb * 32;           // permuted c' base
    __shared__ float ld[32][33];
    int tx = threadIdx.x & 31, ty = threadIdx.x >> 5;
#pragma unroll
    for (int i = 0; i < 4; ++i) {
        int kr = ty + i*8;
        ld[kr][tx] = src[(size_t)kr*2048 + sc0 + tx];
    }
    __syncthreads();
#pragma unroll
    for (int i = 0; i < 4; ++i) {
        int cl = ty + i*8;
        Wt[((size_t)u*G4 + cp0 + cl)*KTOT + k0 + tx] = __float2bfloat16(ld[tx][cl]);
    }
}

// ------------- prep: permuted combined bias -------------
__global__ void k_prep_bias(const float* __restrict__ bi_fw, const float* __restrict__ bh_fw,
                            const float* __restrict__ bi_bw, const float* __restrict__ bh_bw,
                            float* __restrict__ pb) {
    int id = blockIdx.x * 256 + threadIdx.x;
    if (id >= 4*G4) return;
    int u = id >> 11, cp = id & 2047;
    int l = u >> 1, dir = u & 1;
    int jblk = cp >> 7, rr = cp & 127, g = rr >> 5, jin = rr & 31;
    int col = g*512 + jblk*32 + jin;
    const float* bi = dir ? bi_bw : bi_fw;
    const float* bh = dir ? bh_bw : bh_fw;
    pb[id] = bi[l*G4 + col] + bh[l*G4 + col];
}

// ------------- prep: features -> time-major bf16 -------------
__global__ void k_convert_x(const float* __restrict__ f, bf16_t* __restrict__ xbf) {
    int id = blockIdx.x * 256 + threadIdx.x;
    int c8 = id & 63;
    int t  = (id >> 6) & 31;
    int n  = id >> 11;
    const float* s = f + ((size_t)n*WP_ + t)*CH_ + c8*8;
    bf16_t* d = xbf + ((size_t)t*NSEQ + n)*CH_ + c8*8;
#pragma unroll
    for (int i = 0; i < 8; ++i) d[i] = __float2bfloat16(s[i]);
}

// ------------- prep: init h (bf16) / c (f32) from pos_emb -------------
__global__ void k_init_state(const float* __restrict__ pe_fw, const float* __restrict__ pe_bw,
                             bf16_t* __restrict__ hbuf, float* __restrict__ cbuf) {
    int id = blockIdx.x * 256 + threadIdx.x;
    int j = id & 511;
    int n = (id >> 9) & 1023;
    int l = (id >> 19) & 1;
    int dir = id >> 20;
    const float* pe = dir ? pe_bw : pe_fw;
    int rowi = (n & 15) + 1;
    float h = pe[(size_t)rowi*2048 + l*1024 + j];
    float c = pe[(size_t)rowi*2048 + l*1024 + 512 + j];
    int pp = (l == 0) ? 1 : 0;
    hbuf[(size_t)pp*HB_ELEMS + (((size_t)dir*2 + l)*NSEQ + n)*HS_ + j] = __float2bfloat16(h);
    cbuf[(((size_t)dir*2 + l)*NSEQ + n)*HS_ + j] = c;
}

// ------------- phase kernel: {L0 @ t=p, L1 @ t=p-1} x both dirs -------------
// 512 blocks x 512 thr (8 waves). Block = 128 rows x 128 gate-cols, K=1024.
// 16 waves/CU (4/SIMD) for latency hiding; counted-vmcnt(4) pipeline.
__global__ __launch_bounds__(512, 4) void k_phase(
    int p,
    const bf16_t* __restrict__ xbf,
    const bf16_t* __restrict__ Wt,
    const float*  __restrict__ pb,
    bf16_t* __restrict__ hbuf,
    float*  __restrict__ cbuf,
    float*  __restrict__ out) {

    int bx = blockIdx.x;
    int xcd   = bx & 7;
    int layer = (bx >> 8) & 1;
    int r5    = (bx >> 3) & 31;
    int dir   = r5 & 1;
    int cb    = xcd * 2 + ((r5 >> 1) & 1);
    int rb    = r5 >> 2;
    int u     = layer * 2 + dir;

    if (layer == 0 && p >= WP_) return;
    if (layer == 1 && p < 1)    return;

    int row0 = rb * 128;
    int c0 = cb * 128;

    const bf16_t* hread = hbuf + (size_t)((p + 1) & 1) * HB_ELEMS;
    bf16_t* hwrite      = hbuf + (size_t)(p & 1) * HB_ELEMS;

    const bf16_t* A1;
    const bf16_t* A2;
    int t_out = 0;
    if (layer == 0) {
        int t = dir ? (WP_ - 1 - p) : p;
        A1 = xbf + (size_t)t * NSEQ * CH_;
        A2 = hread + ((size_t)dir*2 + 0) * NSEQ * HS_;
    } else {
        A1 = hread + ((size_t)dir*2 + 0) * NSEQ * HS_;   // h0(t=p-1)
        A2 = hread + ((size_t)dir*2 + 1) * NSEQ * HS_;   // h1(t=p-2)
        t_out = dir ? (WP_ - p) : (p - 1);
    }
    const bf16_t* Wu = Wt + (size_t)u * G4 * KTOT;

    __shared__ __align__(16) bf16_t a_lds[2][128*64];
    __shared__ __align__(16) bf16_t b_lds[2][128*64];

    int tid = threadIdx.x;
    int lane = tid & 63;
    int wv = tid >> 6;          // 0..7, each wave owns 16 output rows

    f32x4 acc[8];
#pragma unroll
    for (int n = 0; n < 8; ++n)
        acc[n] = (f32x4){0.f, 0.f, 0.f, 0.f};

    auto STAGE = [&](int kt, int bufi) {
        const bf16_t* Asrc;
        int kloc;
        if (kt < 8) { Asrc = A1; kloc = kt * 64; }
        else        { Asrc = A2; kloc = kt * 64 - 512; }
#pragma unroll
        for (int q = 0; q < 2; ++q) {
            int id = q*512 + tid;
            int r = id >> 3;
            int s = id & 7;
            int kk = ((s ^ (r & 7)) << 3);
            gload16(Asrc + (size_t)(row0 + r)*512 + kloc + kk,
                    a_lds[bufi] + (size_t)(q*512 + (wv << 6)) * 8);
        }
#pragma unroll
        for (int q = 0; q < 2; ++q) {
            int id = q*512 + tid;
            int r = id >> 3;
            int s = id & 7;
            int kk = ((s ^ (r & 7)) << 3);
            gload16(Wu + (size_t)(c0 + r)*KTOT + kt*64 + kk,
                    b_lds[bufi] + (size_t)(q*512 + (wv << 6)) * 8);
        }
    };

    auto COMPUTE = [&](int bufi) {
        const char* ac = (const char*)a_lds[bufi];
        const char* bc = (const char*)b_lds[bufi];
#pragma unroll
        for (int ks = 0; ks < 2; ++ks) {
            int kb = (ks << 5) + ((lane >> 4) << 3);
            bf16x8 av, bv[8];
            {
                int row = (wv << 4) + (lane & 15);
                int byte = row*128 + kb*2;
                byte ^= (row & 7) << 4;
                av = *(const bf16x8*)(ac + byte);
            }
#pragma unroll
            for (int n = 0; n < 8; ++n) {
                int colr = (n << 4) + (lane & 15);
                int byte = colr*128 + kb*2;
                byte ^= (colr & 7) << 4;
                bv[n] = *(const bf16x8*)(bc + byte);
            }
#pragma unroll
            for (int n = 0; n < 8; ++n)
                acc[n] = __builtin_amdgcn_mfma_f32_16x16x32_bf16(av, bv[n], acc[n], 0, 0, 0);
        }
    };

    // prologue: tile 0 in flight (4 VMEM/thread outstanding)
    STAGE(0, 0);
    int cur = 0;
    for (int kt = 0; kt < 15; ++kt) {
        STAGE(kt + 1, cur ^ 1);                       // 8 outstanding
        asm volatile("s_waitcnt vmcnt(4)" ::: "memory");  // tile kt landed; kt+1 in flight
        __builtin_amdgcn_s_barrier();                 // all waves' tile-kt data in LDS
        COMPUTE(cur);                                 // MFMA overlaps tile kt+1 loads
        __builtin_amdgcn_s_barrier();                 // buf[cur] free for reuse
        cur ^= 1;
    }
    asm volatile("s_waitcnt vmcnt(0)" ::: "memory");  // last tile landed
    __builtin_amdgcn_s_barrier();
    COMPUTE(cur);

    // ---- epilogue: lane-local LSTM pointwise ----
    float bias[4][2];
#pragma unroll
    for (int g = 0; g < 4; ++g)
#pragma unroll
        for (int jq = 0; jq < 2; ++jq)
            bias[g][jq] = pb[u*G4 + c0 + g*32 + jq*16 + (lane & 15)];

    float* cptr = cbuf + ((size_t)dir*2 + layer) * NSEQ * HS_;
    bf16_t* hw  = hwrite + ((size_t)dir*2 + layer) * NSEQ * HS_;

#pragma unroll
    for (int jq = 0; jq < 2; ++jq) {
        f32x4 iv = acc[0 + jq];
        f32x4 fv = acc[2 + jq];
        f32x4 ov = acc[4 + jq];
        f32x4 gv = acc[6 + jq];
        int j = cb*32 + jq*16 + (lane & 15);
#pragma unroll
        for (int r = 0; r < 4; ++r) {
            int row = (wv << 4) + ((lane >> 4) << 2) + r;
            int n = row0 + row;
            float ig = sigf(iv[r] + bias[0][jq]);
            float fg = sigf(fv[r] + bias[1][jq]);
            float og = sigf(ov[r] + bias[2][jq]);
            float gg = tanhfast(gv[r] + bias[3][jq]);
            size_t sidx = (size_t)n * HS_ + j;
            float cp = cptr[sidx];
            float cn = fg * cp + ig * gg;
            float hn = og * tanhfast(cn);
            cptr[sidx] = cn;
            hw[sidx] = __float2bfloat16(hn);
            if (layer == 1)
                out[((size_t)n * WP_ + t_out) * (2*HS_) + (size_t)dir*HS_ + j] = hn;
        }
    }
}

extern "C" void kernel_launch(void* const* d_in, const int* in_sizes, int n_in,
                              void* d_out, int out_size, void* d_ws, size_t ws_size,
                              hipStream_t stream) {
    const float* features = (const float*)d_in[0];
    const float* pe_fw = (const float*)d_in[1];
    const float* pe_bw = (const float*)d_in[2];
    const float* Wi_fw = (const float*)d_in[3];
    const float* Wh_fw = (const float*)d_in[4];
    const float* bi_fw = (const float*)d_in[5];
    const float* bh_fw = (const float*)d_in[6];
    const float* Wi_bw = (const float*)d_in[7];
    const float* Wh_bw = (const float*)d_in[8];
    const float* bi_bw = (const float*)d_in[9];
    const float* bh_bw = (const float*)d_in[10];

    char* ws = (char*)d_ws;
    bf16_t* Wt   = (bf16_t*)(ws + WT_OFF);
    bf16_t* xbf  = (bf16_t*)(ws + XBF_OFF);
    bf16_t* hbuf = (bf16_t*)(ws + HBUF_OFF);
    float*  cbuf = (float*)(ws + CBUF_OFF);
    float*  pb   = (float*)(ws + PB_OFF);
    float*  out  = (float*)d_out;

    k_prep_w<<<dim3(8192), dim3(256), 0, stream>>>(Wi_fw, Wh_fw, Wi_bw, Wh_bw, Wt);
    k_prep_bias<<<dim3(32), dim3(256), 0, stream>>>(bi_fw, bh_fw, bi_bw, bh_bw, pb);
    k_convert_x<<<dim3(8192), dim3(256), 0, stream>>>(features, xbf);
    k_init_state<<<dim3(8192), dim3(256), 0, stream>>>(pe_fw, pe_bw, hbuf, cbuf);

    for (int p = 0; p <= WP_; ++p)
        k_phase<<<dim3(512), dim3(512), 0, stream>>>(p, xbf, Wt, pb, hbuf, cbuf, out);
}